// Round 5
// baseline (115.827 us; speedup 1.0000x reference)
//
#include <hip/hip_runtime.h>
#include <hip/hip_bf16.h>
#include <stdint.h>

typedef __attribute__((ext_vector_type(8))) short s16x8;
typedef __attribute__((ext_vector_type(4))) float f32x4;

// ---------------- workspace layout (bytes) ----------------
#define XT_OFF   0u           // xt[b][yx][c] bf16 : 8*4096*256*2 = 16,777,216
#define WT_OFF   16777216u    // Wt tiled bf16     : 72*256*64B   =  1,179,648
#define PW_OFF   17956864u    // pwgt float4       : 8*9*4096*16  =  4,718,592
#define PI_OFF   22675456u    // pidx packed       : 8*9*4096*8   =  2,359,296
#define WS_NEED  25034752u

static __device__ __forceinline__ uint16_t f2bf(float f) {
    __hip_bfloat16 h = __float2bfloat16(f);
    uint16_t u;
    __builtin_memcpy(&u, &h, 2);
    return u;
}
static __device__ __forceinline__ float bflo(uint32_t w) { return __uint_as_float(w << 16); }
static __device__ __forceinline__ float bfhi(uint32_t w) { return __uint_as_float(w & 0xffff0000u); }

// ---------- preprocess 1: x (8,256,64,64) f32 -> xt[b][yx][c] bf16 ----------
__global__ __launch_bounds__(256) void k_transpose_x(const float* __restrict__ x,
                                                     uint16_t* __restrict__ xt) {
    __shared__ float tile[64][65];
    const int blk = blockIdx.x;            // 8*64*4 = 2048
    const int b   = blk >> 8;
    const int yxt = (blk >> 2) & 63;
    const int ct  = blk & 3;
    const int yx0 = yxt << 6, c0 = ct << 6;
    const int tx  = threadIdx.x;
    const int ty  = tx >> 6, lx = tx & 63;
    #pragma unroll
    for (int i = 0; i < 16; ++i) {
        const int c = (i << 2) + ty;
        tile[c][lx] = x[(size_t)((b * 256 + c0 + c) << 12) + yx0 + lx];
    }
    __syncthreads();
    const int cpr = lx & 31;
    #pragma unroll
    for (int i = 0; i < 8; ++i) {
        const int r = (ty << 1) + (lx >> 5) + (i << 3);
        const uint32_t lo = f2bf(tile[2 * cpr][r]);
        const uint32_t hi = f2bf(tile[2 * cpr + 1][r]);
        *(uint32_t*)&xt[(size_t)(b * 4096 + yx0 + r) * 256 + c0 + 2 * cpr] = lo | (hi << 16);
    }
}

// ---------- preprocess 2: weight -> Wt[kb][o][32ch] bf16, A-frag swizzled ----------
__global__ __launch_bounds__(256) void k_prep_w(const float* __restrict__ wgt,
                                                uint16_t* __restrict__ wt) {
    const int o = blockIdx.x;      // 256
    const int c = threadIdx.x;     // 256 (Cin)
    #pragma unroll
    for (int t = 0; t < 9; ++t) {
        const float v = wgt[(size_t)o * 2304 + c * 9 + t];
        const int kb = t * 8 + (c >> 5);
        const int kk = c & 31;
        const uint32_t byte = (uint32_t)kb * 16384u + (uint32_t)o * 64u
            + (uint32_t)(((((kk >> 3) ^ ((o >> 1) & 3)) << 4)) | ((kk & 7) << 1));
        wt[byte >> 1] = f2bf(v);
    }
}

// ---------- preprocess 3: offsets -> bilinear params per (b,t,pixel) ----------
__global__ __launch_bounds__(256) void k_prep_params(const float* __restrict__ off,
                                                     float4* __restrict__ pw,
                                                     uint2* __restrict__ pi) {
    const int blk = blockIdx.x;            // 8*9*16 = 1152
    const int b = blk / 144;
    const int r = blk - b * 144;
    const int t = r >> 4;
    const int p = ((r & 15) << 8) + threadIdx.x;   // 0..4095
    const int u = p >> 6, v = p & 63;
    const int kh = t / 3, kw = t - 3 * kh;
    const float dy = off[(size_t)((b * 18 + 2 * t) << 12) + p];
    const float dx = off[(size_t)((b * 18 + 2 * t + 1) << 12) + p];
    const float py = dy + (float)(u - 1 + kh);
    const float px = dx + (float)(v - 1 + kw);
    const float y0f = floorf(py), x0f = floorf(px);
    const float wy = py - y0f, wx = px - x0f;
    const int y0 = (int)y0f, x0 = (int)x0f;
    const int y1 = y0 + 1, x1 = x0 + 1;
    const bool vy0 = (y0 >= 0) && (y0 < 64);
    const bool vy1 = (y1 >= 0) && (y1 < 64);
    const bool vx0 = (x0 >= 0) && (x0 < 64);
    const bool vx1 = (x1 >= 0) && (x1 < 64);
    const int cy0 = min(max(y0, 0), 63), cy1 = min(max(y1, 0), 63);
    const int cx0 = min(max(x0, 0), 63), cx1 = min(max(x1, 0), 63);
    float4 w4;
    w4.x = (1.f - wy) * (1.f - wx) * ((vy0 && vx0) ? 1.f : 0.f);
    w4.y = (1.f - wy) * wx         * ((vy0 && vx1) ? 1.f : 0.f);
    w4.z = wy * (1.f - wx)         * ((vy1 && vx0) ? 1.f : 0.f);
    w4.w = wy * wx                 * ((vy1 && vx1) ? 1.f : 0.f);
    uint2 id;
    id.x = (uint32_t)(cy0 * 64 + cx0) | ((uint32_t)(cy0 * 64 + cx1) << 16);
    id.y = (uint32_t)(cy1 * 64 + cx0) | ((uint32_t)(cy1 * 64 + cx1) << 16);
    const size_t o_ = (size_t)(b * 9 + t) * 4096 + p;
    pw[o_] = w4;
    pi[o_] = id;
}

// ---------- main: 256 Cout x 64 pix; T14 register-staged im2col + W 3-ring ----------
#define W_DMA(KB, BUF) do {                                                       \
    const char* gw_ = (const char*)wt + (size_t)(KB) * 16384u;                    \
    char* lw_ = (char*)&w_lds[BUF][0];                                            \
    _Pragma("unroll")                                                             \
    for (int it_ = 0; it_ < 2; ++it_) {                                           \
        const int seg_ = wv * 2 + it_;                                            \
        __builtin_amdgcn_global_load_lds(                                         \
            (const __attribute__((address_space(1))) void*)(gw_ + seg_ * 1024 + lane * 16), \
            (__attribute__((address_space(3))) void*)(lw_ + seg_ * 1024), 16, 0, 0); \
    }                                                                             \
} while (0)

// one K-step: counted wait -> barrier -> issue W(kb+2) -> frags -> 8 MFMA
#define KSTEP(KB, N) do {                                                         \
    asm volatile("s_waitcnt vmcnt(" #N ") lgkmcnt(0)" ::: "memory");              \
    __builtin_amdgcn_s_barrier();                                                 \
    __builtin_amdgcn_sched_barrier(0);                                            \
    if ((KB) + 2 < 72) W_DMA((KB) + 2, ((KB) + 2) % 3);                           \
    {                                                                             \
        const int s_ = (KB) & 7;                                                  \
        const char* wb_ = (const char*)&w_lds[(KB) % 3][0];                       \
        s16x8 afr[4], bfr[2];                                                     \
        _Pragma("unroll")                                                         \
        for (int m = 0; m < 4; ++m) afr[m] = *(const s16x8*)(wb_ + a_off + m * 1024); \
        _Pragma("unroll")                                                         \
        for (int j = 0; j < 2; ++j) {                                             \
            const int pix_  = wp * 32 + j * 16 + l15;                             \
            const int boff_ = pix_ * 512 + (((s_ * 4 + kp) ^ (l15 & 7)) << 4);    \
            bfr[j] = *(const s16x8*)((const char*)im2col + boff_);                \
        }                                                                         \
        __builtin_amdgcn_s_setprio(1);                                            \
        _Pragma("unroll")                                                         \
        for (int m = 0; m < 4; ++m)                                               \
            _Pragma("unroll")                                                     \
            for (int j = 0; j < 2; ++j)                                           \
                acc[m][j] = __builtin_amdgcn_mfma_f32_16x16x32_bf16(afr[m], bfr[j], acc[m][j], 0, 0, 0); \
        __builtin_amdgcn_s_setprio(0);                                            \
    }                                                                             \
} while (0)

// issue corner loads for staged pixels [P0..P0+3] (16 vmcnt entries)
#define CBURST(P0) do {                                                           \
    _Pragma("unroll")                                                             \
    for (int i = 0; i < 4; ++i) {                                                 \
        const uint2 id_ = pin[(P0) + i];                                          \
        cA[i] = *(const uint2*)(xb + (id_.x & 0xffffu) * 256u + lane * 4);        \
        cB[i] = *(const uint2*)(xb + (id_.x >> 16)     * 256u + lane * 4);        \
        cC[i] = *(const uint2*)(xb + (id_.y & 0xffffu) * 256u + lane * 4);        \
        cD[i] = *(const uint2*)(xb + (id_.y >> 16)     * 256u + lane * 4);        \
    }                                                                             \
} while (0)

// blend burst -> rr[P0..P0+3] (register-only)
#define CBLEND(P0) do {                                                           \
    _Pragma("unroll")                                                             \
    for (int i = 0; i < 4; ++i) {                                                 \
        const float4 w4_ = pwn[(P0) + i];                                         \
        uint2 r_;                                                                 \
        { const float lo = w4_.x * bflo(cA[i].x) + w4_.y * bflo(cB[i].x)          \
                         + w4_.z * bflo(cC[i].x) + w4_.w * bflo(cD[i].x);         \
          const float hi = w4_.x * bfhi(cA[i].x) + w4_.y * bfhi(cB[i].x)          \
                         + w4_.z * bfhi(cC[i].x) + w4_.w * bfhi(cD[i].x);         \
          r_.x = (uint32_t)f2bf(lo) | ((uint32_t)f2bf(hi) << 16); }               \
        { const float lo = w4_.x * bflo(cA[i].y) + w4_.y * bflo(cB[i].y)          \
                         + w4_.z * bflo(cC[i].y) + w4_.w * bflo(cD[i].y);         \
          const float hi = w4_.x * bfhi(cA[i].y) + w4_.y * bfhi(cB[i].y)          \
                         + w4_.z * bfhi(cC[i].y) + w4_.w * bfhi(cD[i].y);         \
          r_.y = (uint32_t)f2bf(lo) | ((uint32_t)f2bf(hi) << 16); }               \
        rr[(P0) + i] = r_;                                                        \
    }                                                                             \
} while (0)

#define LOAD_PARAMS(TT) do {                                                      \
    _Pragma("unroll")                                                             \
    for (int i = 0; i < 8; ++i) {                                                 \
        const int lp_ = wv * 8 + i;                                               \
        const int ui_ = __builtin_amdgcn_readfirstlane((b * 9 + (TT)) * 4096 + pix0 + lp_); \
        pin[i] = pi[ui_];                                                         \
        pwn[i] = pw[ui_];                                                         \
    }                                                                             \
} while (0)

#define DS_WRITE_RR() do {                                                        \
    _Pragma("unroll")                                                             \
    for (int i = 0; i < 8; ++i) {                                                 \
        const int lp_ = wv * 8 + i;                                               \
        const int slot_ = (lane >> 1) ^ (lp_ & 7);                                \
        *(uint2*)((char*)im2col + lp_ * 512 + slot_ * 16 + (lane & 1) * 8) = rr[i]; \
    }                                                                             \
} while (0)

__global__ __launch_bounds__(512, 4) void k_main(const uint16_t* __restrict__ xt,
                                                 const uint16_t* __restrict__ wt,
                                                 const float4* __restrict__ pw,
                                                 const uint2* __restrict__ pi,
                                                 const float* __restrict__ bias,
                                                 float* __restrict__ out) {
    __shared__ uint16_t w_lds[3][8192];      // 3 x 16KB weight ring
    __shared__ uint16_t im2col[64 * 256];    // 32KB: [pix][256ch], slot-swizzled

    const int orig = blockIdx.x;                      // 512 blocks
    const int bid  = (orig & 7) * 64 + (orig >> 3);   // XCD swizzle: one batch/XCD
    const int b    = bid >> 6;
    const int pix0 = (bid & 63) << 6;

    const int tx   = threadIdx.x;
    const int lane = tx & 63;
    const int wv   = tx >> 6;        // wave 0..7
    const int wc   = wv & 3;         // cout quadrant (64 couts)
    const int wp   = wv >> 2;        // pixel half (32 pixels)
    const int l15  = lane & 15;
    const int kp   = lane >> 4;

    const int ar    = wc * 64 + l15;
    const int a_off = ar * 64 + ((kp ^ ((ar >> 1) & 3)) << 4);

    const uint16_t* xb = xt + (size_t)b * 4096 * 256;

    uint2  pin[8];
    float4 pwn[8];
    uint2  cA[4], cB[4], cC[4], cD[4];
    uint2  rr[8];

    f32x4 acc[4][2];
    #pragma unroll
    for (int m = 0; m < 4; ++m)
        #pragma unroll
        for (int j = 0; j < 2; ++j) acc[m][j] = (f32x4){0.f, 0.f, 0.f, 0.f};

    // ---- prologue: stage tap 0 directly; prime W(0),W(1) ----
    LOAD_PARAMS(0);
    CBURST(0);
    asm volatile("s_waitcnt vmcnt(0)" ::: "memory");
    CBLEND(0);
    CBURST(4);
    W_DMA(0, 0);
    W_DMA(1, 1);
    asm volatile("s_waitcnt vmcnt(4)" ::: "memory");   // burst2 done; W(0),W(1) in flight
    CBLEND(4);
    DS_WRITE_RR();
    // step-0 KSTEP supplies lgkmcnt(0)+barrier to publish the writes

    // ---- taps 0..7: compute tap t while register-staging tap t+1 ----
    #pragma unroll 1
    for (int t = 0; t < 8; ++t) {
        LOAD_PARAMS(t + 1);
        CBURST(0);                       // 16 entries, newest
        KSTEP(t * 8 + 0, 18);            // newer: W(+1)=2 + burst1=16
        KSTEP(t * 8 + 1, 18);            // newer: burst1=16 + W(+2)=2
        KSTEP(t * 8 + 2, 2);             // newer: W(+3)=2 (forces burst1 done)
        KSTEP(t * 8 + 3, 2);
        asm volatile("s_waitcnt vmcnt(4)" ::: "memory");   // W(+4),W(+5) in flight
        CBLEND(0);
        CBURST(4);
        KSTEP(t * 8 + 4, 18);            // newer: W(+5)=2 + burst2=16
        KSTEP(t * 8 + 5, 18);
        KSTEP(t * 8 + 6, 2);
        KSTEP(t * 8 + 7, 2);
        asm volatile("s_waitcnt vmcnt(4)" ::: "memory");   // W(+8),W(+9) in flight
        CBLEND(4);
        asm volatile("s_waitcnt lgkmcnt(0)" ::: "memory");
        __builtin_amdgcn_s_barrier();    // all waves done reading im2col(t)
        __builtin_amdgcn_sched_barrier(0);
        DS_WRITE_RR();                   // write im2col(t+1)
    }

    // ---- tap 8: pure compute ----
    KSTEP(64, 2); KSTEP(65, 2); KSTEP(66, 2); KSTEP(67, 2);
    KSTEP(68, 2); KSTEP(69, 2); KSTEP(70, 2); KSTEP(71, 0);

    // ---- epilogue: bias + store ----
    #pragma unroll
    for (int m = 0; m < 4; ++m) {
        #pragma unroll
        for (int q = 0; q < 4; ++q) {
            const int o = wc * 64 + m * 16 + kp * 4 + q;
            const float bv = bias[o];
            float* orow = out + (((size_t)(b * 256 + o)) << 12) + pix0 + wp * 32;
            #pragma unroll
            for (int j = 0; j < 2; ++j)
                orow[j * 16 + l15] = acc[m][j][q] + bv;
        }
    }
}

// ================= fallback fp32 kernel (round-1, known-correct) =================
#define KTOT 2304
#define KCF  32
#define WROW 260
#define AROW 72

__global__ __launch_bounds__(256) void deform_conv_fallback(
    const float* __restrict__ x, const float* __restrict__ off,
    const float* __restrict__ wgt, const float* __restrict__ bias,
    float* __restrict__ out) {
    __shared__ float  w_lds[KCF][WROW];
    __shared__ float  a_lds[KCF][AROW];
    __shared__ int4   pidx[9][64];
    __shared__ float4 pwgt[9][64];
    const int tx = threadIdx.x;
    const int blk = blockIdx.x;
    const int b = blk >> 6, u = blk & 63;
    for (int item = tx; item < 9 * 64; item += 256) {
        const int t = item >> 6, p = item & 63;
        const int k = t / 3, l = t - 3 * k;
        const float dy = off[((b * 18 + 2 * t) << 12) + u * 64 + p];
        const float dx = off[((b * 18 + 2 * t + 1) << 12) + u * 64 + p];
        const float py = dy + (float)(u - 1 + k);
        const float px = dx + (float)(p - 1 + l);
        const float y0f = floorf(py), x0f = floorf(px);
        const float wy = py - y0f, wx = px - x0f;
        const int y0 = (int)y0f, x0 = (int)x0f, y1 = y0 + 1, x1 = x0 + 1;
        const bool vy0 = (y0 >= 0) && (y0 < 64), vy1 = (y1 >= 0) && (y1 < 64);
        const bool vx0 = (x0 >= 0) && (x0 < 64), vx1 = (x1 >= 0) && (x1 < 64);
        const int cy0 = min(max(y0, 0), 63), cy1 = min(max(y1, 0), 63);
        const int cx0 = min(max(x0, 0), 63), cx1 = min(max(x1, 0), 63);
        int4 id; id.x = cy0 * 64 + cx0; id.y = cy0 * 64 + cx1;
        id.z = cy1 * 64 + cx0; id.w = cy1 * 64 + cx1;
        float4 w4;
        w4.x = (1.f - wy) * (1.f - wx) * ((vy0 && vx0) ? 1.f : 0.f);
        w4.y = (1.f - wy) * wx * ((vy0 && vx1) ? 1.f : 0.f);
        w4.z = wy * (1.f - wx) * ((vy1 && vx0) ? 1.f : 0.f);
        w4.w = wy * wx * ((vy1 && vx1) ? 1.f : 0.f);
        pidx[t][p] = id; pwgt[t][p] = w4;
    }
    const int og = tx & 31, pgr = tx >> 5;
    float acc[8][8];
    #pragma unroll
    for (int j = 0; j < 8; ++j)
        #pragma unroll
        for (int q = 0; q < 8; ++q) acc[j][q] = 0.f;
    __syncthreads();
    for (int kb = 0; kb < 72; ++kb) {
        const int k0 = kb * KCF;
        #pragma unroll
        for (int it = 0; it < 8; ++it) {
            const int item = it * 256 + tx;
            const int o = item >> 3, jj = item & 7;
            const float4 v = *(const float4*)&wgt[o * KTOT + k0 + jj * 4];
            w_lds[jj * 4 + 0][o] = v.x; w_lds[jj * 4 + 1][o] = v.y;
            w_lds[jj * 4 + 2][o] = v.z; w_lds[jj * 4 + 3][o] = v.w;
        }
        #pragma unroll
        for (int it = 0; it < 8; ++it) {
            const int item = it * 256 + tx;
            const int kk = item >> 6, p = item & 63;
            const int kg = k0 + kk;
            const int c = kg / 9, t = kg - 9 * c;
            const float* plane = x + ((b * 256 + c) << 12);
            const int4 id = pidx[t][p];
            const float4 w4 = pwgt[t][p];
            float v = w4.x * plane[id.x] + w4.y * plane[id.y]
                    + w4.z * plane[id.z] + w4.w * plane[id.w];
            a_lds[kk][p] = v;
        }
        __syncthreads();
        #pragma unroll 2
        for (int kk = 0; kk < KCF; ++kk) {
            const float4 w0 = *(const float4*)&w_lds[kk][og * 8];
            const float4 w1 = *(const float4*)&w_lds[kk][og * 8 + 4];
            const float4 a0 = *(const float4*)&a_lds[kk][pgr * 8];
            const float4 a1 = *(const float4*)&a_lds[kk][pgr * 8 + 4];
            const float wv[8] = {w0.x, w0.y, w0.z, w0.w, w1.x, w1.y, w1.z, w1.w};
            const float av[8] = {a0.x, a0.y, a0.z, a0.w, a1.x, a1.y, a1.z, a1.w};
            #pragma unroll
            for (int j = 0; j < 8; ++j)
                #pragma unroll
                for (int q = 0; q < 8; ++q) acc[j][q] += wv[j] * av[q];
        }
        __syncthreads();
    }
    const int vb = pgr * 8;
    #pragma unroll
    for (int j = 0; j < 8; ++j) {
        const int o = og * 8 + j;
        const float bv = bias[o];
        float* op = out + ((b * 256 + o) << 12) + u * 64 + vb;
        float4 r0, r1;
        r0.x = acc[j][0] + bv; r0.y = acc[j][1] + bv; r0.z = acc[j][2] + bv; r0.w = acc[j][3] + bv;
        r1.x = acc[j][4] + bv; r1.y = acc[j][5] + bv; r1.z = acc[j][6] + bv; r1.w = acc[j][7] + bv;
        *(float4*)op = r0; *(float4*)(op + 4) = r1;
    }
}

extern "C" void kernel_launch(void* const* d_in, const int* in_sizes, int n_in,
                              void* d_out, int out_size, void* d_ws, size_t ws_size,
                              hipStream_t stream) {
    const float* x    = (const float*)d_in[0];
    const float* off  = (const float*)d_in[1];
    const float* wgt  = (const float*)d_in[2];
    const float* bias = (const float*)d_in[3];
    float* out = (float*)d_out;

    if (ws_size < WS_NEED) {
        deform_conv_fallback<<<dim3(512), dim3(256), 0, stream>>>(x, off, wgt, bias, out);
        return;
    }
    uint16_t* xt  = (uint16_t*)((char*)d_ws + XT_OFF);
    uint16_t* wtp = (uint16_t*)((char*)d_ws + WT_OFF);
    float4*   pwp = (float4*)((char*)d_ws + PW_OFF);
    uint2*    pip = (uint2*)((char*)d_ws + PI_OFF);

    k_transpose_x <<<dim3(2048), dim3(256), 0, stream>>>(x, xt);
    k_prep_w      <<<dim3(256),  dim3(256), 0, stream>>>(wgt, wtp);
    k_prep_params <<<dim3(1152), dim3(256), 0, stream>>>(off, pwp, pip);
    k_main        <<<dim3(512),  dim3(512), 0, stream>>>(xt, wtp, pwp, pip, bias, out);
}

// Round 6
// 85.378 us; speedup vs baseline: 1.3566x; 1.3566x over previous
//
#include <hip/hip_runtime.h>
#include <hip/hip_bf16.h>
#include <stdint.h>

typedef __attribute__((ext_vector_type(8))) short s16x8;
typedef __attribute__((ext_vector_type(4))) float f32x4;

// ---------------- workspace layout (bytes) ----------------
#define XT_OFF   0u           // xt[b][yx][c] bf16 : 8*4096*256*2 = 16,777,216
#define WT_OFF   16777216u    // Wt frag-layout bf16: 72*16384B   =  1,179,648
#define PW_OFF   17956864u    // pwgt float4       : 8*9*4096*16  =  4,718,592
#define PI_OFF   22675456u    // pidx packed       : 8*9*4096*8   =  2,359,296
#define WS_NEED  25034752u

static __device__ __forceinline__ uint16_t f2bf(float f) {
    __hip_bfloat16 h = __float2bfloat16(f);
    uint16_t u;
    __builtin_memcpy(&u, &h, 2);
    return u;
}
static __device__ __forceinline__ float bflo(uint32_t w) { return __uint_as_float(w << 16); }
static __device__ __forceinline__ float bfhi(uint32_t w) { return __uint_as_float(w & 0xffff0000u); }
static __device__ __forceinline__ float rdl(float v, int l) {
    return __uint_as_float((uint32_t)__builtin_amdgcn_readlane((int)__float_as_uint(v), l));
}

// ---------- preprocess 1: x (8,256,64,64) f32 -> xt[b][yx][c] bf16 ----------
__global__ __launch_bounds__(256) void k_transpose_x(const float* __restrict__ x,
                                                     uint16_t* __restrict__ xt) {
    __shared__ float tile[64][65];
    const int blk = blockIdx.x;            // 8*64*4 = 2048
    const int b   = blk >> 8;
    const int yxt = (blk >> 2) & 63;
    const int ct  = blk & 3;
    const int yx0 = yxt << 6, c0 = ct << 6;
    const int tx  = threadIdx.x;
    const int ty  = tx >> 6, lx = tx & 63;
    #pragma unroll
    for (int i = 0; i < 16; ++i) {
        const int c = (i << 2) + ty;
        tile[c][lx] = x[(size_t)((b * 256 + c0 + c) << 12) + yx0 + lx];
    }
    __syncthreads();
    const int cpr = lx & 31;
    #pragma unroll
    for (int i = 0; i < 8; ++i) {
        const int r = (ty << 1) + (lx >> 5) + (i << 3);
        const uint32_t lo = f2bf(tile[2 * cpr][r]);
        const uint32_t hi = f2bf(tile[2 * cpr + 1][r]);
        *(uint32_t*)&xt[(size_t)(b * 4096 + yx0 + r) * 256 + c0 + 2 * cpr] = lo | (hi << 16);
    }
}

// ---------- preprocess 2: weight -> A-fragment layout wt2[kb][wc][m][lane][16B] ----------
// afr(kb,wc,m) lane l: couts o = wc*64+m*16+(l&15), ch = (kb&7)*32+(l>>4)*8..+7, tap = kb>>3
__global__ __launch_bounds__(256) void k_prep_w(const float* __restrict__ wgt,
                                                uint16_t* __restrict__ wt) {
    const int blk = blockIdx.x;            // 288 = kb(72) x wc(4)
    const int kb = blk >> 2, wc = blk & 3;
    const int m = threadIdx.x >> 6, lane = threadIdx.x & 63;
    const int o = wc * 64 + m * 16 + (lane & 15);
    const int t = kb >> 3;
    const int ch0 = (kb & 7) * 32 + (lane >> 4) * 8;
    uint32_t pk[4];
    #pragma unroll
    for (int q = 0; q < 4; ++q) {
        const float v0 = wgt[(size_t)o * 2304 + (size_t)(ch0 + 2 * q) * 9 + t];
        const float v1 = wgt[(size_t)o * 2304 + (size_t)(ch0 + 2 * q + 1) * 9 + t];
        pk[q] = (uint32_t)f2bf(v0) | ((uint32_t)f2bf(v1) << 16);
    }
    uint4 r; r.x = pk[0]; r.y = pk[1]; r.z = pk[2]; r.w = pk[3];
    *(uint4*)((char*)wt + (size_t)kb * 16384 + wc * 4096 + m * 1024 + lane * 16) = r;
}

// ---------- preprocess 3: offsets -> bilinear params per (b,t,pixel) ----------
__global__ __launch_bounds__(256) void k_prep_params(const float* __restrict__ off,
                                                     float4* __restrict__ pw,
                                                     uint2* __restrict__ pi) {
    const int blk = blockIdx.x;            // 8*9*16 = 1152
    const int b = blk / 144;
    const int r = blk - b * 144;
    const int t = r >> 4;
    const int p = ((r & 15) << 8) + threadIdx.x;   // 0..4095
    const int u = p >> 6, v = p & 63;
    const int kh = t / 3, kw = t - 3 * kh;
    const float dy = off[(size_t)((b * 18 + 2 * t) << 12) + p];
    const float dx = off[(size_t)((b * 18 + 2 * t + 1) << 12) + p];
    const float py = dy + (float)(u - 1 + kh);
    const float px = dx + (float)(v - 1 + kw);
    const float y0f = floorf(py), x0f = floorf(px);
    const float wy = py - y0f, wx = px - x0f;
    const int y0 = (int)y0f, x0 = (int)x0f;
    const int y1 = y0 + 1, x1 = x0 + 1;
    const bool vy0 = (y0 >= 0) && (y0 < 64);
    const bool vy1 = (y1 >= 0) && (y1 < 64);
    const bool vx0 = (x0 >= 0) && (x0 < 64);
    const bool vx1 = (x1 >= 0) && (x1 < 64);
    const int cy0 = min(max(y0, 0), 63), cy1 = min(max(y1, 0), 63);
    const int cx0 = min(max(x0, 0), 63), cx1 = min(max(x1, 0), 63);
    float4 w4;
    w4.x = (1.f - wy) * (1.f - wx) * ((vy0 && vx0) ? 1.f : 0.f);
    w4.y = (1.f - wy) * wx         * ((vy0 && vx1) ? 1.f : 0.f);
    w4.z = wy * (1.f - wx)         * ((vy1 && vx0) ? 1.f : 0.f);
    w4.w = wy * wx                 * ((vy1 && vx1) ? 1.f : 0.f);
    uint2 id;
    id.x = (uint32_t)(cy0 * 64 + cx0) | ((uint32_t)(cy0 * 64 + cx1) << 16);
    id.y = (uint32_t)(cy1 * 64 + cx0) | ((uint32_t)(cy1 * 64 + cx1) << 16);
    const size_t o_ = (size_t)(b * 9 + t) * 4096 + p;
    pw[o_] = w4;
    pi[o_] = id;
}

// ---------- main: 256 Cout x 128 px per block; W in regs, im2col dbuf, 1 barrier/tap ----------

// blend corner regs (parity PAR, px slot IDX in pair) -> bf16 pair, ds_write to inxt
#define BLENDPX(PAR, IDX, LP, PXL) do {                                           \
    const float wqa = rdl(pwv.x, (PXL)), wqb = rdl(pwv.y, (PXL));                 \
    const float wqc = rdl(pwv.z, (PXL)), wqd = rdl(pwv.w, (PXL));                 \
    const uint2 A_ = cr[PAR][(IDX)*4+0], B_ = cr[PAR][(IDX)*4+1];                 \
    const uint2 C_ = cr[PAR][(IDX)*4+2], D_ = cr[PAR][(IDX)*4+3];                 \
    uint2 r_;                                                                     \
    { const float lo = wqa * bflo(A_.x) + wqb * bflo(B_.x)                        \
                     + wqc * bflo(C_.x) + wqd * bflo(D_.x);                       \
      const float hi = wqa * bfhi(A_.x) + wqb * bfhi(B_.x)                        \
                     + wqc * bfhi(C_.x) + wqd * bfhi(D_.x);                       \
      r_.x = (uint32_t)f2bf(lo) | ((uint32_t)f2bf(hi) << 16); }                   \
    { const float lo = wqa * bflo(A_.y) + wqb * bflo(B_.y)                        \
                     + wqc * bflo(C_.y) + wqd * bflo(D_.y);                       \
      const float hi = wqa * bfhi(A_.y) + wqb * bfhi(B_.y)                        \
                     + wqc * bfhi(C_.y) + wqd * bfhi(D_.y);                       \
      r_.y = (uint32_t)f2bf(lo) | ((uint32_t)f2bf(hi) << 16); }                   \
    const int slot_ = (lane >> 1) ^ ((LP) & 7);                                   \
    *(uint2*)(inxt + (LP) * 512 + slot_ * 16 + (lane & 1) * 8) = r_;              \
} while (0)

// one K-step (T,S literals): issue corners pair[S], prefetch W(kb+1),
// blend pair[S-1], bfr reads + 16 MFMA
#define STEP(T, S, STG) do {                                                      \
    const int kb_ = (T) * 8 + (S);                                                \
    if (STG) {                                                                    \
        const uint32_t ixA = (uint32_t)__builtin_amdgcn_readlane((int)piv.x, 2*(S));     \
        const uint32_t iyA = (uint32_t)__builtin_amdgcn_readlane((int)piv.y, 2*(S));     \
        const uint32_t ixB = (uint32_t)__builtin_amdgcn_readlane((int)piv.x, 2*(S)+1);   \
        const uint32_t iyB = (uint32_t)__builtin_amdgcn_readlane((int)piv.y, 2*(S)+1);   \
        cr[(S)&1][0] = *(const uint2*)(xb + (ixA & 0xffffu) * 256u + lane * 4);   \
        cr[(S)&1][1] = *(const uint2*)(xb + (ixA >> 16)     * 256u + lane * 4);   \
        cr[(S)&1][2] = *(const uint2*)(xb + (iyA & 0xffffu) * 256u + lane * 4);   \
        cr[(S)&1][3] = *(const uint2*)(xb + (iyA >> 16)     * 256u + lane * 4);   \
        cr[(S)&1][4] = *(const uint2*)(xb + (ixB & 0xffffu) * 256u + lane * 4);   \
        cr[(S)&1][5] = *(const uint2*)(xb + (ixB >> 16)     * 256u + lane * 4);   \
        cr[(S)&1][6] = *(const uint2*)(xb + (iyB & 0xffffu) * 256u + lane * 4);   \
        cr[(S)&1][7] = *(const uint2*)(xb + (iyB >> 16)     * 256u + lane * 4);   \
    }                                                                             \
    if (kb_ < 71) {                                                               \
        _Pragma("unroll")                                                         \
        for (int m = 0; m < 4; ++m)                                               \
            wA[((S)+1)&1][m] = *(const s16x8*)(wfrag + (size_t)(kb_+1) * 16384 + m * 1024); \
    }                                                                             \
    if ((STG) && (S) >= 1) {                                                      \
        BLENDPX(((S)-1)&1, 0, wv * 16 + 2*((S)-1),     2*((S)-1));                \
        BLENDPX(((S)-1)&1, 1, wv * 16 + 2*((S)-1) + 1, 2*((S)-1)+1);              \
    }                                                                             \
    {                                                                             \
        s16x8 bfr[4];                                                             \
        _Pragma("unroll")                                                         \
        for (int j = 0; j < 4; ++j)                                               \
            bfr[j] = *(const s16x8*)(icur + rb0 + j * 8192 + so[S]);              \
        __builtin_amdgcn_s_setprio(1);                                            \
        _Pragma("unroll")                                                         \
        for (int m = 0; m < 4; ++m)                                               \
            _Pragma("unroll")                                                     \
            for (int j = 0; j < 4; ++j)                                           \
                acc[m][j] = __builtin_amdgcn_mfma_f32_16x16x32_bf16(wA[(S)&1][m], bfr[j], acc[m][j], 0, 0, 0); \
        __builtin_amdgcn_s_setprio(0);                                            \
    }                                                                             \
} while (0)

__global__ __launch_bounds__(512, 2) void k_main(const uint16_t* __restrict__ xt,
                                                 const uint16_t* __restrict__ wt,
                                                 const float4* __restrict__ pw,
                                                 const uint2* __restrict__ pi,
                                                 const float* __restrict__ bias,
                                                 float* __restrict__ out) {
    __shared__ uint16_t imc[2][128 * 256];   // 2 x 64KB im2col double-buffer

    const int orig = blockIdx.x;                      // 256 blocks
    const int bid  = (orig & 7) * 32 + (orig >> 3);   // XCD swizzle: one batch/XCD
    const int b    = bid >> 5;
    const int pix0 = (bid & 31) << 7;                 // 128-px tile

    const int tx   = threadIdx.x;
    const int lane = tx & 63;
    const int wv   = tx >> 6;        // wave 0..7
    const int wc   = wv & 3;         // cout quadrant (64 couts)
    const int wn   = wv >> 2;        // pixel half (64 px)
    const int l15  = lane & 15;
    const int kp   = lane >> 4;

    const uint16_t* xb = xt + (size_t)b * 4096 * 256;
    const char* wfrag = (const char*)wt + (size_t)wc * 4096 + (size_t)lane * 16;

    // ds_read byte offsets: row (wn*64 + j*16 + l15)*512, slot ((s*4+kp)^(l15&7))<<4
    int so[8];
    #pragma unroll
    for (int s = 0; s < 8; ++s) so[s] = ((s * 4 + kp) ^ (l15 & 7)) << 4;
    const int rb0 = (wn * 64 + l15) * 512;

    f32x4 acc[4][4];
    #pragma unroll
    for (int m = 0; m < 4; ++m)
        #pragma unroll
        for (int j = 0; j < 4; ++j) acc[m][j] = (f32x4){0.f, 0.f, 0.f, 0.f};

    // ---- prologue: stage tap 0 (16 px per wave) into imc[0] ----
    #pragma unroll
    for (int i = 0; i < 16; ++i) {
        const int lp = wv * 16 + i;
        const int ui = __builtin_amdgcn_readfirstlane(b * 9 * 4096 + pix0 + lp);
        const uint2  id = pi[ui];
        const float4 w4 = pw[ui];
        const uint2 A  = *(const uint2*)(xb + (id.x & 0xffffu) * 256u + lane * 4);
        const uint2 Bv = *(const uint2*)(xb + (id.x >> 16)     * 256u + lane * 4);
        const uint2 Cv = *(const uint2*)(xb + (id.y & 0xffffu) * 256u + lane * 4);
        const uint2 Dv = *(const uint2*)(xb + (id.y >> 16)     * 256u + lane * 4);
        uint2 r;
        { const float lo = w4.x * bflo(A.x) + w4.y * bflo(Bv.x)
                         + w4.z * bflo(Cv.x) + w4.w * bflo(Dv.x);
          const float hi = w4.x * bfhi(A.x) + w4.y * bfhi(Bv.x)
                         + w4.z * bfhi(Cv.x) + w4.w * bfhi(Dv.x);
          r.x = (uint32_t)f2bf(lo) | ((uint32_t)f2bf(hi) << 16); }
        { const float lo = w4.x * bflo(A.y) + w4.y * bflo(Bv.y)
                         + w4.z * bflo(Cv.y) + w4.w * bflo(Dv.y);
          const float hi = w4.x * bfhi(A.y) + w4.y * bfhi(Bv.y)
                         + w4.z * bfhi(Cv.y) + w4.w * bfhi(Dv.y);
          r.y = (uint32_t)f2bf(lo) | ((uint32_t)f2bf(hi) << 16); }
        const int slot = (lane >> 1) ^ (lp & 7);
        *(uint2*)((char*)&imc[0][0] + lp * 512 + slot * 16 + (lane & 1) * 8) = r;
    }

    // W fragment prefetch for kb=0
    s16x8 wA[2][4];
    #pragma unroll
    for (int m = 0; m < 4; ++m) wA[0][m] = *(const s16x8*)(wfrag + m * 1024);

    uint2  cr[2][8];
    uint2  piv = {0, 0};
    float4 pwv = {0.f, 0.f, 0.f, 0.f};

    // ---- taps 0..7: compute tap t, stage tap t+1 (pair-pipelined, no mid-tap barrier) ----
    #pragma unroll 1
    for (int t = 0; t < 8; ++t) {
        __syncthreads();   // publish imc[t&1]
        const char* icur = (const char*)&imc[t & 1][0];
        char*       inxt = (char*)&imc[(t + 1) & 1][0];
        {   // params for tap t+1 (lane -> px lane&15 of this wave's 16)
            const int idx = (b * 9 + t + 1) * 4096 + pix0 + wv * 16 + l15;
            piv = pi[idx];
            pwv = pw[idx];
        }
        STEP(t, 0, 1); STEP(t, 1, 1); STEP(t, 2, 1); STEP(t, 3, 1);
        STEP(t, 4, 1); STEP(t, 5, 1); STEP(t, 6, 1); STEP(t, 7, 1);
        // boundary: blend last pair (7) into imc[(t+1)&1]
        BLENDPX(1, 0, wv * 16 + 14, 14);
        BLENDPX(1, 1, wv * 16 + 15, 15);
    }

    // ---- tap 8: pure compute ----
    __syncthreads();
    {
        const char* icur = (const char*)&imc[0][0];
        char*       inxt = (char*)&imc[1][0];   // unused
        (void)inxt;
        STEP(8, 0, 0); STEP(8, 1, 0); STEP(8, 2, 0); STEP(8, 3, 0);
        STEP(8, 4, 0); STEP(8, 5, 0); STEP(8, 6, 0); STEP(8, 7, 0);
    }

    // ---- epilogue: bias + store ----
    #pragma unroll
    for (int m = 0; m < 4; ++m) {
        #pragma unroll
        for (int q = 0; q < 4; ++q) {
            const int o = wc * 64 + m * 16 + kp * 4 + q;
            const float bv = bias[o];
            float* orow = out + (((size_t)(b * 256 + o)) << 12) + pix0 + wn * 64;
            #pragma unroll
            for (int j = 0; j < 4; ++j)
                orow[j * 16 + l15] = acc[m][j][q] + bv;
        }
    }
}

// ================= fallback fp32 kernel (round-1, known-correct) =================
#define KTOT 2304
#define KCF  32
#define WROW 260
#define AROW 72

__global__ __launch_bounds__(256) void deform_conv_fallback(
    const float* __restrict__ x, const float* __restrict__ off,
    const float* __restrict__ wgt, const float* __restrict__ bias,
    float* __restrict__ out) {
    __shared__ float  w_lds[KCF][WROW];
    __shared__ float  a_lds[KCF][AROW];
    __shared__ int4   pidx[9][64];
    __shared__ float4 pwgt[9][64];
    const int tx = threadIdx.x;
    const int blk = blockIdx.x;
    const int b = blk >> 6, u = blk & 63;
    for (int item = tx; item < 9 * 64; item += 256) {
        const int t = item >> 6, p = item & 63;
        const int k = t / 3, l = t - 3 * k;
        const float dy = off[((b * 18 + 2 * t) << 12) + u * 64 + p];
        const float dx = off[((b * 18 + 2 * t + 1) << 12) + u * 64 + p];
        const float py = dy + (float)(u - 1 + k);
        const float px = dx + (float)(p - 1 + l);
        const float y0f = floorf(py), x0f = floorf(px);
        const float wy = py - y0f, wx = px - x0f;
        const int y0 = (int)y0f, x0 = (int)x0f, y1 = y0 + 1, x1 = x0 + 1;
        const bool vy0 = (y0 >= 0) && (y0 < 64), vy1 = (y1 >= 0) && (y1 < 64);
        const bool vx0 = (x0 >= 0) && (x0 < 64), vx1 = (x1 >= 0) && (x1 < 64);
        const int cy0 = min(max(y0, 0), 63), cy1 = min(max(y1, 0), 63);
        const int cx0 = min(max(x0, 0), 63), cx1 = min(max(x1, 0), 63);
        int4 id; id.x = cy0 * 64 + cx0; id.y = cy0 * 64 + cx1;
        id.z = cy1 * 64 + cx0; id.w = cy1 * 64 + cx1;
        float4 w4;
        w4.x = (1.f - wy) * (1.f - wx) * ((vy0 && vx0) ? 1.f : 0.f);
        w4.y = (1.f - wy) * wx * ((vy0 && vx1) ? 1.f : 0.f);
        w4.z = wy * (1.f - wx) * ((vy1 && vx0) ? 1.f : 0.f);
        w4.w = wy * wx * ((vy1 && vx1) ? 1.f : 0.f);
        pidx[t][p] = id; pwgt[t][p] = w4;
    }
    const int og = tx & 31, pgr = tx >> 5;
    float acc[8][8];
    #pragma unroll
    for (int j = 0; j < 8; ++j)
        #pragma unroll
        for (int q = 0; q < 8; ++q) acc[j][q] = 0.f;
    __syncthreads();
    for (int kb = 0; kb < 72; ++kb) {
        const int k0 = kb * KCF;
        #pragma unroll
        for (int it = 0; it < 8; ++it) {
            const int item = it * 256 + tx;
            const int o = item >> 3, jj = item & 7;
            const float4 v = *(const float4*)&wgt[o * KTOT + k0 + jj * 4];
            w_lds[jj * 4 + 0][o] = v.x; w_lds[jj * 4 + 1][o] = v.y;
            w_lds[jj * 4 + 2][o] = v.z; w_lds[jj * 4 + 3][o] = v.w;
        }
        #pragma unroll
        for (int it = 0; it < 8; ++it) {
            const int item = it * 256 + tx;
            const int kk = item >> 6, p = item & 63;
            const int kg = k0 + kk;
            const int c = kg / 9, t = kg - 9 * c;
            const float* plane = x + ((b * 256 + c) << 12);
            const int4 id = pidx[t][p];
            const float4 w4 = pwgt[t][p];
            float v = w4.x * plane[id.x] + w4.y * plane[id.y]
                    + w4.z * plane[id.z] + w4.w * plane[id.w];
            a_lds[kk][p] = v;
        }
        __syncthreads();
        #pragma unroll 2
        for (int kk = 0; kk < KCF; ++kk) {
            const float4 w0 = *(const float4*)&w_lds[kk][og * 8];
            const float4 w1 = *(const float4*)&w_lds[kk][og * 8 + 4];
            const float4 a0 = *(const float4*)&a_lds[kk][pgr * 8];
            const float4 a1 = *(const float4*)&a_lds[kk][pgr * 8 + 4];
            const float wv[8] = {w0.x, w0.y, w0.z, w0.w, w1.x, w1.y, w1.z, w1.w};
            const float av[8] = {a0.x, a0.y, a0.z, a0.w, a1.x, a1.y, a1.z, a1.w};
            #pragma unroll
            for (int j = 0; j < 8; ++j)
                #pragma unroll
                for (int q = 0; q < 8; ++q) acc[j][q] += wv[j] * av[q];
        }
        __syncthreads();
    }
    const int vb = pgr * 8;
    #pragma unroll
    for (int j = 0; j < 8; ++j) {
        const int o = og * 8 + j;
        const float bv = bias[o];
        float* op = out + ((b * 256 + o) << 12) + u * 64 + vb;
        float4 r0, r1;
        r0.x = acc[j][0] + bv; r0.y = acc[j][1] + bv; r0.z = acc[j][2] + bv; r0.w = acc[j][3] + bv;
        r1.x = acc[j][4] + bv; r1.y = acc[j][5] + bv; r1.z = acc[j][6] + bv; r1.w = acc[j][7] + bv;
        *(float4*)op = r0; *(float4*)(op + 4) = r1;
    }
}

extern "C" void kernel_launch(void* const* d_in, const int* in_sizes, int n_in,
                              void* d_out, int out_size, void* d_ws, size_t ws_size,
                              hipStream_t stream) {
    const float* x    = (const float*)d_in[0];
    const float* off  = (const float*)d_in[1];
    const float* wgt  = (const float*)d_in[2];
    const float* bias = (const float*)d_in[3];
    float* out = (float*)d_out;

    if (ws_size < WS_NEED) {
        deform_conv_fallback<<<dim3(512), dim3(256), 0, stream>>>(x, off, wgt, bias, out);
        return;
    }
    uint16_t* xt  = (uint16_t*)((char*)d_ws + XT_OFF);
    uint16_t* wtp = (uint16_t*)((char*)d_ws + WT_OFF);
    float4*   pwp = (float4*)((char*)d_ws + PW_OFF);
    uint2*    pip = (uint2*)((char*)d_ws + PI_OFF);

    k_transpose_x <<<dim3(2048), dim3(256), 0, stream>>>(x, xt);
    k_prep_w      <<<dim3(288),  dim3(256), 0, stream>>>(wgt, wtp);
    k_prep_params <<<dim3(1152), dim3(256), 0, stream>>>(off, pwp, pip);
    k_main        <<<dim3(256),  dim3(512), 0, stream>>>(xt, wtp, pwp, pip, bias, out);
}